// Round 1
// baseline (53.373 us; speedup 1.0000x reference)
//
#include <hip/hip_runtime.h>

// RandomShiftsAug: edge-pad by 4 then dynamic crop at (sy, sx) per image.
// out[n,c,i,j] = x[n,c, clamp(i+sy-4), clamp(j+sx-4)]
// Pure memory-bound gather: 130 MB in + 130 MB out.

constexpr int N = 512, C = 9, H = 84, W = 84, P = 4;
constexpr int HW = H * W;
constexpr int TOTAL = N * C * HW;   // 32,514,048 f32
constexpr int W4 = W / 4;           // 21 float4 per row (rows 16B-aligned)
constexpr int TOTAL4 = TOTAL / 4;   // 8,128,512 float4 stores

__global__ __launch_bounds__(256) void shift_aug_kernel(
    const float* __restrict__ x, const int* __restrict__ shift,
    float* __restrict__ out) {
  const int stride = gridDim.x * blockDim.x;
  for (int idx = blockIdx.x * blockDim.x + threadIdx.x; idx < TOTAL4;
       idx += stride) {
    int q  = idx / W4;                 // (n*C + c)*H + i
    int j0 = (idx - q * W4) * 4;       // output col of first element
    int i  = q % H;
    int nc = q / H;
    int n  = nc / C;

    int sx = shift[2 * n + 0];
    int sy = shift[2 * n + 1];

    int si = i + sy - P;
    si = si < 0 ? 0 : (si > H - 1 ? H - 1 : si);
    const float* __restrict__ row = x + (size_t)nc * HW + (size_t)si * W;

    int jb = j0 + sx - P;              // source col of first element
    float4 v;
    int j;
    j = jb + 0; j = j < 0 ? 0 : (j > W - 1 ? W - 1 : j); v.x = row[j];
    j = jb + 1; j = j < 0 ? 0 : (j > W - 1 ? W - 1 : j); v.y = row[j];
    j = jb + 2; j = j < 0 ? 0 : (j > W - 1 ? W - 1 : j); v.z = row[j];
    j = jb + 3; j = j < 0 ? 0 : (j > W - 1 ? W - 1 : j); v.w = row[j];

    *reinterpret_cast<float4*>(out + (size_t)idx * 4) = v;
  }
}

extern "C" void kernel_launch(void* const* d_in, const int* in_sizes, int n_in,
                              void* d_out, int out_size, void* d_ws,
                              size_t ws_size, hipStream_t stream) {
  const float* x     = (const float*)d_in[0];
  const int*   shift = (const int*)d_in[1];
  float*       out   = (float*)d_out;

  const int block = 256;
  int grid = 2048;  // grid-stride; ~16 float4 per thread
  shift_aug_kernel<<<grid, block, 0, stream>>>(x, shift, out);
}

// Round 2
// 43.703 us; speedup vs baseline: 1.2213x; 1.2213x over previous
//
#include <hip/hip_runtime.h>

// RandomShiftsAug: edge-pad by 4 then dynamic crop at (sy, sx) per image.
// out[n,c,i,j] = x[n,c, clamp(i+sy-4), clamp(j+sx-4)]
// Memory-bound gather; R2: minimize vmem instruction count.

constexpr int N = 512, C = 9, H = 84, W = 84, P = 4;
constexpr int HW = H * W;
constexpr int W4 = W / 4;                  // 21 float4 per row
constexpr int TOTAL4 = N * C * H * W4;     // 8,128,512 float4 stores

typedef float f4 __attribute__((ext_vector_type(4)));

__global__ __launch_bounds__(256) void shift_aug_kernel(
    const float* __restrict__ x, const int* __restrict__ shift,
    float* __restrict__ out) {
  const int stride = gridDim.x * blockDim.x;
  for (int idx = blockIdx.x * blockDim.x + threadIdx.x; idx < TOTAL4;
       idx += stride) {
    int q  = idx / W4;                 // (n*C + c)*H + i
    int j0 = (idx - q * W4) * 4;       // output col of first element
    int i  = q % H;
    int nc = q / H;
    int n  = nc / C;

    int2 s = *reinterpret_cast<const int2*>(shift + 2 * n);  // one 8B load
    int sx = s.x, sy = s.y;

    int si = i + sy - P;
    si = si < 0 ? 0 : (si > H - 1 ? H - 1 : si);
    const float* __restrict__ row = x + (size_t)nc * HW + (size_t)si * W;

    int jb = j0 + sx - P;              // source col of first element
    f4 v;
    if ((unsigned)jb <= (unsigned)(W - 4)) {
      // Interior: whole float4 in-bounds. 4B-aligned 16B load -> dwordx4.
      __builtin_memcpy(&v, row + jb, sizeof(f4));
    } else {
      // Border (only j0==0 or j0==80 can land here): per-element clamp.
      int j;
      j = jb + 0; j = j < 0 ? 0 : (j > W - 1 ? W - 1 : j); v.x = row[j];
      j = jb + 1; j = j < 0 ? 0 : (j > W - 1 ? W - 1 : j); v.y = row[j];
      j = jb + 2; j = j < 0 ? 0 : (j > W - 1 ? W - 1 : j); v.z = row[j];
      j = jb + 3; j = j < 0 ? 0 : (j > W - 1 ? W - 1 : j); v.w = row[j];
    }
    // Write-once output: keep it out of L2/L3 so the input stays resident.
    __builtin_nontemporal_store(v, reinterpret_cast<f4*>(out) + idx);
  }
}

extern "C" void kernel_launch(void* const* d_in, const int* in_sizes, int n_in,
                              void* d_out, int out_size, void* d_ws,
                              size_t ws_size, hipStream_t stream) {
  const float* x     = (const float*)d_in[0];
  const int*   shift = (const int*)d_in[1];
  float*       out   = (float*)d_out;

  const int block = 256;
  int grid = 2048;  // grid-stride; ~15.5 float4 per thread
  shift_aug_kernel<<<grid, block, 0, stream>>>(x, shift, out);
}